// Round 12
// baseline (2100.439 us; speedup 1.0000x reference)
//
#include <hip/hip_runtime.h>
#include <hip/hip_fp16.h>

#define B_  32
#define T_  2048
#define I_  256
#define H_  128

typedef _Float16 f16;
typedef _Float16 f16x2 __attribute__((ext_vector_type(2)));
typedef _Float16 f16x4 __attribute__((ext_vector_type(4)));
typedef _Float16 f16x8 __attribute__((ext_vector_type(8)));
typedef float    f32x4 __attribute__((ext_vector_type(4)));

#if __has_builtin(__builtin_amdgcn_fdot2)
#define FDOT2(a, b, c) __builtin_amdgcn_fdot2((a), (b), (c), false)
#else
static __device__ __forceinline__ float FDOT2(f16x2 a, f16x2 b, float c) {
  return c + (float)a[0] * (float)b[0] + (float)a[1] * (float)b[1];
}
#endif

static __device__ __forceinline__ f16x2 asf16x2(unsigned u) {
  return __builtin_bit_cast(f16x2, u);
}

// Cross-lane via DPP quad_perm (VALU pipe -- NOT the DS pipe like shfl/bpermute)
//   xor1: [1,0,3,2]=0xB1   xor2: [2,3,0,1]=0x4E   xor3: [3,2,1,0]=0x1B
#define DPPF(x, ctrl)                                                      \
  __builtin_bit_cast(float, __builtin_amdgcn_mov_dpp(                      \
      __builtin_bit_cast(int, (x)), (ctrl), 0xF, 0xF, true))

static __device__ __forceinline__ float fast_sig(float x) {
  float e = __builtin_amdgcn_exp2f(-1.44269504089f * x);
  return __builtin_amdgcn_rcpf(1.0f + e);
}
static __device__ __forceinline__ float fast_tanh(float x) {
  float e = __builtin_amdgcn_exp2f(-2.88539008178f * x);
  return 2.0f * __builtin_amdgcn_rcpf(1.0f + e) - 1.0f;
}

// LDS-only barrier (no vmcnt drain).  sched_barrier fences per rule #18.
#define BARRIER_LDS()                                   \
  __builtin_amdgcn_sched_barrier(0);                    \
  asm volatile("s_waitcnt lgkmcnt(0)" ::: "memory");    \
  __builtin_amdgcn_s_barrier();                         \
  __builtin_amdgcn_sched_barrier(0)

#define MFMA16(a, b, c) __builtin_amdgcn_mfma_f32_16x16x32_f16((a), (b), (c), 0, 0, 0)

// ---------------------------------------------------------------------------
// Kernel 1: xg[m][col], col = dir*512 + unit*4 + gate  (gate 0=i 1=f 2=g 3=o)
//   value = x[m]·W_ih[grow] + b_ih[grow] + b_hh[grow], grow = gate*128+unit.
//   (unchanged)
// ---------------------------------------------------------------------------
__global__ __launch_bounds__(256) void xg_gemm(
    const float* __restrict__ x,
    const float* __restrict__ Wf, const float* __restrict__ Wb,
    const float* __restrict__ bf_ih, const float* __restrict__ bf_hh,
    const float* __restrict__ bb_ih, const float* __restrict__ bb_hh,
    f16* __restrict__ xg)
{
  __shared__ f16 xs[128][136];   // +8 f16 pad
  __shared__ f16 wt[128][136];

  const int tid = threadIdx.x;
  const int m0  = blockIdx.y * 128;
  const int n0  = blockIdx.x * 128;

  const float* Wsrc; const float* bih; const float* bhh; int nb; size_t dbase;
  if (n0 < 512) { Wsrc = Wf; bih = bf_ih; bhh = bf_hh; nb = n0;       dbase = 0; }
  else          { Wsrc = Wb; bih = bb_ih; bhh = bb_hh; nb = n0 - 512; dbase = 512; }

  const int w  = tid >> 6;
  const int l  = tid & 63;
  const int lr = l & 15;
  const int lk = (l >> 4) * 8;

  f32x4 acc[2][8] = {};

  #pragma unroll
  for (int kh = 0; kh < 2; ++kh) {
    #pragma unroll
    for (int it = 0; it < 16; ++it) {
      int idx = it * 256 + tid;
      int row = idx >> 5, c4 = idx & 31;
      float4 v = *(const float4*)&x[(size_t)(m0 + row) * I_ + kh * 128 + c4 * 4];
      f16x4 h4 = { (f16)v.x, (f16)v.y, (f16)v.z, (f16)v.w };
      *(f16x4*)&xs[row][c4 * 4] = h4;
    }
    #pragma unroll
    for (int it = 0; it < 16; ++it) {
      int idx = it * 256 + tid;
      int row = idx >> 5, c4 = idx & 31;
      float4 v = *(const float4*)&Wsrc[(size_t)(nb + row) * I_ + kh * 128 + c4 * 4];
      f16x4 h4 = { (f16)v.x, (f16)v.y, (f16)v.z, (f16)v.w };
      *(f16x4*)&wt[row][c4 * 4] = h4;
    }
    __syncthreads();

    #pragma unroll
    for (int ks = 0; ks < 4; ++ks) {
      int kk = ks * 32 + lk;
      f16x8 a0 = *(const f16x8*)&xs[w * 32 + lr][kk];
      f16x8 a1 = *(const f16x8*)&xs[w * 32 + 16 + lr][kk];
      #pragma unroll
      for (int nt = 0; nt < 8; ++nt) {
        f16x8 bf = *(const f16x8*)&wt[nt * 16 + lr][kk];
        acc[0][nt] = MFMA16(a0, bf, acc[0][nt]);
        acc[1][nt] = MFMA16(a1, bf, acc[1][nt]);
      }
    }
    __syncthreads();
  }

  // epilogue: D row = (l>>4)*4 + r, col = l&15; scatter to unit-major layout
  #pragma unroll
  for (int mt = 0; mt < 2; ++mt) {
    #pragma unroll
    for (int nt = 0; nt < 8; ++nt) {
      int nloc = nt * 16 + lr;
      int grow = nb + nloc;                 // gate-row within dir, 0..511
      int gate = grow >> 7, unit = grow & 127;
      size_t col = dbase + (size_t)unit * 4 + gate;
      float bias = bih[grow] + bhh[grow];
      #pragma unroll
      for (int r = 0; r < 4; ++r) {
        int m = m0 + w * 32 + mt * 16 + (l >> 4) * 4 + r;
        xg[(size_t)m * 1024 + col] = (f16)(acc[mt][nt][r] + bias);
      }
    }
  }
}

// ---------------------------------------------------------------------------
// Kernel 2: recurrence -- R11 lane structure, TWO phase-overlapped chains/WG.
//   32 WGs x 512 thr.  WG wg: dir = wg>>4, batches bA = (wg&15)*2, bB = bA+1.
//   Both chains share dir -> ONE weight register set (64 f16x2 words).
//   Per step: A-dots, B-dots (B's issue fills A's serial-latency tail),
//   A-finish, B-finish, ONE barrier for both chains.
//   Lane map (per R11): sl = (l&3)|((l>>5)<<2) K-slice; g = w*8+((l>>2)&7);
//   owned row r = g*8+sl = unit*4+gate.  K-reduce: xor1/xor2 quad-perm DPP
//   + one shfl_xor(32).  Gate gather: xor1/2/3 DPP within the lane quad.
// ---------------------------------------------------------------------------
__global__ __launch_bounds__(512, 1) void birnn_rec(
    const f16* __restrict__ xg,
    const float* __restrict__ Wfhh, const float* __restrict__ Wbhh,
    const int* __restrict__ lengths,
    float* __restrict__ out)
{
  const int tid = threadIdx.x;
  const int w   = tid >> 6;
  const int l   = tid & 63;
  const int sl  = (l & 3) | ((l >> 5) << 2);   // K-slice 0..7
  const int g   = w * 8 + ((l >> 2) & 7);      // row group 0..63
  const int r   = g * 8 + sl;                  // owned logical row 0..511
  const int uu  = r >> 2;                      // unit 0..127
  const int gg  = r & 3;                       // gate (== l&3)
  const int wg  = blockIdx.x;                  // 0..31
  const int dir = wg >> 4;
  const int bA  = (wg & 15) * 2;
  const int bB  = bA + 1;
  const float* Whh = dir ? Wbhh : Wfhh;
  const int LA  = lengths[bA];
  const int LB  = lengths[bB];

  // wrg[j][k]: logical row g*8+(j^sl), cols sl*16 + 2k..2k+1 (shared by A,B)
  unsigned wrg[8][8];
  #pragma unroll
  for (int j = 0; j < 8; ++j) {
    int lrow = g * 8 + (j ^ sl);
    const float* src = &Whh[(size_t)((lrow & 3) * 128 + (lrow >> 2)) * H_ + sl * 16];
    #pragma unroll
    for (int k4 = 0; k4 < 4; ++k4) {
      float4 v = *(const float4*)&src[k4 * 4];
      wrg[j][2 * k4]     = __builtin_bit_cast(unsigned, (f16x2){ (f16)v.x, (f16)v.y });
      wrg[j][2 * k4 + 1] = __builtin_bit_cast(unsigned, (f16x2){ (f16)v.z, (f16)v.w });
    }
  }

  __shared__ __align__(16) f16 hbufA[2][128];
  __shared__ __align__(16) f16 hbufB[2][128];
  if (tid < 128) { hbufA[0][tid] = (f16)0.0f; hbufB[0][tid] = (f16)0.0f; }
  float cA = 0.0f, cB = 0.0f;
  __syncthreads();

  auto rowofA = [&](int t) -> size_t {
    int it = t;
    if (dir) it = (t < LA) ? (LA - 1 - t) : t;
    return (size_t)(bA * T_ + it) * 1024 + (size_t)dir * 512 + (size_t)r;
  };
  auto rowofB = [&](int t) -> size_t {
    int it = t;
    if (dir) it = (t < LB) ? (LB - 1 - t) : t;
    return (size_t)(bB * T_ + it) * 1024 + (size_t)dir * 512 + (size_t)r;
  };

  // depth-2 xg prefetch per chain (named slots)
  f16 paA = xg[rowofA(0)], pbA = xg[rowofA(1)];
  f16 paB = xg[rowofB(0)], pbB = xg[rowofB(1)];

  const float bscale = (gg == 2) ? 2.0f : 1.0f;   // gate g -> tanh = 2*sig(2x)-1
  const float bmul   = (gg == 2) ? 2.0f : 1.0f;
  const float badd   = (gg == 2) ? -1.0f : 0.0f;
  const bool  writer = (gg == 0);

#define DOTS(hbuf, RB, P)                                                    \
    uint4 hA_##P = *(const uint4*)&hbuf[RB][sl * 16];                        \
    uint4 hB_##P = *(const uint4*)&hbuf[RB][sl * 16 + 8];                    \
    float P[8] = { 0.f, 0.f, 0.f, 0.f, 0.f, 0.f, 0.f, 0.f };                 \
    _Pragma("unroll")                                                        \
    for (int j = 0; j < 8; ++j) {                                            \
      P[j] = FDOT2(asf16x2(hA_##P.x), asf16x2(wrg[j][0]), P[j]);             \
      P[j] = FDOT2(asf16x2(hA_##P.y), asf16x2(wrg[j][1]), P[j]);             \
      P[j] = FDOT2(asf16x2(hA_##P.z), asf16x2(wrg[j][2]), P[j]);             \
      P[j] = FDOT2(asf16x2(hA_##P.w), asf16x2(wrg[j][3]), P[j]);             \
      P[j] = FDOT2(asf16x2(hB_##P.x), asf16x2(wrg[j][4]), P[j]);             \
      P[j] = FDOT2(asf16x2(hB_##P.y), asf16x2(wrg[j][5]), P[j]);             \
      P[j] = FDOT2(asf16x2(hB_##P.z), asf16x2(wrg[j][6]), P[j]);             \
      P[j] = FDOT2(asf16x2(hB_##P.w), asf16x2(wrg[j][7]), P[j]);             \
    }

#define FINISH(P, xv, cS, hbuf, WB, bX, t)                                   \
  {                                                                          \
    P[0] += DPPF(P[1], 0xB1);                                                \
    P[2] += DPPF(P[3], 0xB1);                                                \
    P[4] += DPPF(P[5], 0xB1);                                                \
    P[6] += DPPF(P[7], 0xB1);                                                \
    P[0] += DPPF(P[2], 0x4E);                                                \
    P[4] += DPPF(P[6], 0x4E);                                                \
    P[0] += __shfl_xor(P[4], 32, 64);                                        \
    float sum = P[0] + (xv);                                                 \
    float act = fast_sig(bscale * sum) * bmul + badd;                        \
    float a1 = DPPF(act, 0xB1);                                              \
    float a2 = DPPF(act, 0x4E);                                              \
    float a3 = DPPF(act, 0x1B);                                              \
    cS = a1 * cS + act * a2;                                                 \
    float hval = a3 * fast_tanh(cS);                                         \
    if (writer) {                                                            \
      hbuf[WB][uu] = (f16)hval;                                              \
      out[(size_t)((bX) * T_ + (t)) * 256 + dir * 128 + uu] = hval;          \
    }                                                                        \
  }

#define STEP2(t, PA, PB, RB, WB)                                             \
  {                                                                          \
    float xvA = (float)(PA);                                                 \
    float xvB = (float)(PB);                                                 \
    if ((t) + 2 < T_) {                                                      \
      PA = xg[rowofA((t) + 2)];                                              \
      PB = xg[rowofB((t) + 2)];                                              \
    }                                                                        \
    DOTS(hbufA, RB, pA)                                                      \
    DOTS(hbufB, RB, pB)                                                      \
    FINISH(pA, xvA, cA, hbufA, WB, bA, t)                                    \
    FINISH(pB, xvB, cB, hbufB, WB, bB, t)                                    \
    BARRIER_LDS();                                                           \
  }

  for (int tt = 0; tt < T_; tt += 2) {
    STEP2(tt,     paA, paB, 0, 1)
    STEP2(tt + 1, pbA, pbB, 1, 0)
  }
#undef STEP2
#undef FINISH
#undef DOTS
}

// ---------------------------------------------------------------------------
extern "C" void kernel_launch(void* const* d_in, const int* in_sizes, int n_in,
                              void* d_out, int out_size, void* d_ws, size_t ws_size,
                              hipStream_t stream) {
  const float* x      = (const float*)d_in[0];
  const int*   lengths= (const int*)  d_in[1];
  const float* Wf_ih  = (const float*)d_in[2];
  const float* Wf_hh  = (const float*)d_in[3];
  const float* bf_ih  = (const float*)d_in[4];
  const float* bf_hh  = (const float*)d_in[5];
  const float* Wb_ih  = (const float*)d_in[6];
  const float* Wb_hh  = (const float*)d_in[7];
  const float* bb_ih  = (const float*)d_in[8];
  const float* bb_hh  = (const float*)d_in[9];
  float* out = (float*)d_out;
  f16*   xg  = (f16*)d_ws;   // needs B*T*1024*2 = 134,217,728 bytes

  (void)in_sizes; (void)n_in; (void)out_size; (void)ws_size;

  xg_gemm<<<dim3(8, 512), 256, 0, stream>>>(x, Wf_ih, Wb_ih,
                                            bf_ih, bf_hh, bb_ih, bb_hh, xg);
  birnn_rec<<<dim3(32), 512, 0, stream>>>(xg, Wf_hh, Wb_hh, lengths, out);
}

// Round 13
// 1387.992 us; speedup vs baseline: 1.5133x; 1.5133x over previous
//
#include <hip/hip_runtime.h>
#include <hip/hip_fp16.h>

#define B_  32
#define T_  2048
#define I_  256
#define H_  128

typedef _Float16 f16;
typedef _Float16 f16x2 __attribute__((ext_vector_type(2)));
typedef _Float16 f16x4 __attribute__((ext_vector_type(4)));
typedef _Float16 f16x8 __attribute__((ext_vector_type(8)));
typedef float    f32x4 __attribute__((ext_vector_type(4)));

static __device__ __forceinline__ float fast_sig(float x) {
  float e = __builtin_amdgcn_exp2f(-1.44269504089f * x);
  return __builtin_amdgcn_rcpf(1.0f + e);
}
static __device__ __forceinline__ float fast_tanh(float x) {
  float e = __builtin_amdgcn_exp2f(-2.88539008178f * x);
  return 2.0f * __builtin_amdgcn_rcpf(1.0f + e) - 1.0f;
}

// LDS-only barrier (no vmcnt drain).  sched_barrier fences per rule #18.
#define BARRIER_LDS()                                   \
  __builtin_amdgcn_sched_barrier(0);                    \
  asm volatile("s_waitcnt lgkmcnt(0)" ::: "memory");    \
  __builtin_amdgcn_s_barrier();                         \
  __builtin_amdgcn_sched_barrier(0)

#define MFMA16(a, b, c) __builtin_amdgcn_mfma_f32_16x16x32_f16((a), (b), (c), 0, 0, 0)

// ---------------------------------------------------------------------------
// Kernel 1: xg[m][col], col = dir*512 + unit*4 + gate  (gate 0=i 1=f 2=g 3=o)
//   value = x[m]·W_ih[grow] + b_ih[grow] + b_hh[grow], grow = gate*128+unit.
//   (unchanged -- passes, ~150 us)
// ---------------------------------------------------------------------------
__global__ __launch_bounds__(256) void xg_gemm(
    const float* __restrict__ x,
    const float* __restrict__ Wf, const float* __restrict__ Wb,
    const float* __restrict__ bf_ih, const float* __restrict__ bf_hh,
    const float* __restrict__ bb_ih, const float* __restrict__ bb_hh,
    f16* __restrict__ xg)
{
  __shared__ f16 xs[128][136];   // +8 f16 pad
  __shared__ f16 wt[128][136];

  const int tid = threadIdx.x;
  const int m0  = blockIdx.y * 128;
  const int n0  = blockIdx.x * 128;

  const float* Wsrc; const float* bih; const float* bhh; int nb; size_t dbase;
  if (n0 < 512) { Wsrc = Wf; bih = bf_ih; bhh = bf_hh; nb = n0;       dbase = 0; }
  else          { Wsrc = Wb; bih = bb_ih; bhh = bb_hh; nb = n0 - 512; dbase = 512; }

  const int w  = tid >> 6;
  const int l  = tid & 63;
  const int lr = l & 15;
  const int lk = (l >> 4) * 8;

  f32x4 acc[2][8] = {};

  #pragma unroll
  for (int kh = 0; kh < 2; ++kh) {
    #pragma unroll
    for (int it = 0; it < 16; ++it) {
      int idx = it * 256 + tid;
      int row = idx >> 5, c4 = idx & 31;
      float4 v = *(const float4*)&x[(size_t)(m0 + row) * I_ + kh * 128 + c4 * 4];
      f16x4 h4 = { (f16)v.x, (f16)v.y, (f16)v.z, (f16)v.w };
      *(f16x4*)&xs[row][c4 * 4] = h4;
    }
    #pragma unroll
    for (int it = 0; it < 16; ++it) {
      int idx = it * 256 + tid;
      int row = idx >> 5, c4 = idx & 31;
      float4 v = *(const float4*)&Wsrc[(size_t)(nb + row) * I_ + kh * 128 + c4 * 4];
      f16x4 h4 = { (f16)v.x, (f16)v.y, (f16)v.z, (f16)v.w };
      *(f16x4*)&wt[row][c4 * 4] = h4;
    }
    __syncthreads();

    #pragma unroll
    for (int ks = 0; ks < 4; ++ks) {
      int kk = ks * 32 + lk;
      f16x8 a0 = *(const f16x8*)&xs[w * 32 + lr][kk];
      f16x8 a1 = *(const f16x8*)&xs[w * 32 + 16 + lr][kk];
      #pragma unroll
      for (int nt = 0; nt < 8; ++nt) {
        f16x8 bf = *(const f16x8*)&wt[nt * 16 + lr][kk];
        acc[0][nt] = MFMA16(a0, bf, acc[0][nt]);
        acc[1][nt] = MFMA16(a1, bf, acc[1][nt]);
      }
    }
    __syncthreads();
  }

  // epilogue: D row = (l>>4)*4 + r, col = l&15; scatter to unit-major layout
  #pragma unroll
  for (int mt = 0; mt < 2; ++mt) {
    #pragma unroll
    for (int nt = 0; nt < 8; ++nt) {
      int nloc = nt * 16 + lr;
      int grow = nb + nloc;                 // gate-row within dir, 0..511
      int gate = grow >> 7, unit = grow & 127;
      size_t col = dbase + (size_t)unit * 4 + gate;
      float bias = bih[grow] + bhh[grow];
      #pragma unroll
      for (int r = 0; r < 4; ++r) {
        int m = m0 + w * 32 + mt * 16 + (l >> 4) * 4 + r;
        xg[(size_t)m * 1024 + col] = (f16)(acc[mt][nt][r] + bias);
      }
    }
  }
}

// ---------------------------------------------------------------------------
// Kernel 2: recurrence via MFMA, W-stationary, zero-C, lane-split activations.
//   64 WGs x 512 thr (8 waves), one chain per WG.
//   gates(512) = W_hh·h via mfma_f32_16x16x32_f16:
//     A = W tile (16 gate-rows x 32 k), STATIONARY in registers (loaded once):
//         lane holds A[row=l&15][k=(l>>4)*8+e], 4 tiles x 4 k-chunks = 64 regs.
//     B = h broadcast (cols identical): lane reads h[(l>>4)*8+e+kc*32] --
//         4x ds_read_b128 from hbuf, conflict-free broadcast.
//     C = loop-invariant ZERO (no per-step acc init).
//   Per tile: 2 independent 2-deep MFMA chains + one f32x4 add.
//   D layout (rows unit-major r=unit*4+gate): lane holds regs 0..3 =
//   i,f,g,o of unit w*16 + q*4 + (l>>4) for each tile q -- no cross-lane
//   reduce or gather AT ALL.  The 16 redundant D columns (j=l&15) are split:
//   lane activates tile q=j&3 only (2-level f32x4 cndmask select, static).
//   Writers j<4 publish h (ds_write_b16) + out.  ONE LDS-only barrier/step.
// ---------------------------------------------------------------------------
__global__ __launch_bounds__(512, 1) void birnn_rec(
    const f16* __restrict__ xg,
    const float* __restrict__ Wfhh, const float* __restrict__ Wbhh,
    const int* __restrict__ lengths,
    float* __restrict__ out)
{
  const int tid = threadIdx.x;
  const int w   = tid >> 6;
  const int l   = tid & 63;
  const int j   = l & 15;        // D column copy
  const int rg  = l >> 4;        // row-group (unit within tile quad)
  const int q   = j & 3;         // tile this lane activates
  const int dir = blockIdx.x >> 5;
  const int b   = blockIdx.x & 31;
  const float* Whh = dir ? Wbhh : Wfhh;
  const int L   = lengths[b];

  const int uu  = w * 16 + q * 4 + rg;   // unit this lane activates

  // Stationary A-fragments: wf[qt][kc] = W rows w*64+qt*16+(l&15),
  // k = kc*32 + (l>>4)*8 .. +8.  Logical row r -> physical (r&3)*128+(r>>2).
  f16x8 wf[4][4];
  #pragma unroll
  for (int qt = 0; qt < 4; ++qt) {
    int rlog = w * 64 + qt * 16 + j;
    const float* wrow = &Whh[(size_t)((rlog & 3) * 128 + (rlog >> 2)) * H_];
    #pragma unroll
    for (int kc = 0; kc < 4; ++kc) {
      int k0 = kc * 32 + rg * 8;
      float4 va = *(const float4*)&wrow[k0];
      float4 vb = *(const float4*)&wrow[k0 + 4];
      wf[qt][kc] = (f16x8){ (f16)va.x, (f16)va.y, (f16)va.z, (f16)va.w,
                            (f16)vb.x, (f16)vb.y, (f16)vb.z, (f16)vb.w };
    }
  }

  __shared__ __align__(16) f16 hbuf[2][128];
  if (tid < 128) hbuf[0][tid] = (f16)0.0f;
  float c = 0.0f;
  const f32x4 ZED = { 0.f, 0.f, 0.f, 0.f };
  __syncthreads();

  auto rowof = [&](int t) -> size_t {
    int it = t;
    if (dir) it = (t < L) ? (L - 1 - t) : t;
    return (size_t)(b * T_ + it) * 1024 + (size_t)dir * 512;
  };

  // depth-2 xg prefetch: this lane's unit's 4 gates = one 8B load
  uint2 pa = *(const uint2*)(xg + rowof(0) + (size_t)uu * 4);
  uint2 pb = *(const uint2*)(xg + rowof(1) + (size_t)uu * 4);

  const bool writer = (j < 4);

#define STEP(t, P, RB, WB)                                                   \
  {                                                                          \
    f16x4 xv = __builtin_bit_cast(f16x4, P);                                 \
    if ((t) + 2 < T_)                                                        \
      P = *(const uint2*)(xg + rowof((t) + 2) + (size_t)uu * 4);             \
    f16x8 h0 = *(const f16x8*)&hbuf[RB][rg * 8];                             \
    f16x8 h1 = *(const f16x8*)&hbuf[RB][rg * 8 + 32];                        \
    f16x8 h2 = *(const f16x8*)&hbuf[RB][rg * 8 + 64];                        \
    f16x8 h3 = *(const f16x8*)&hbuf[RB][rg * 8 + 96];                        \
    f32x4 s0[4], s1[4];                                                      \
    _Pragma("unroll")                                                        \
    for (int qt = 0; qt < 4; ++qt) {                                         \
      s0[qt] = MFMA16(wf[qt][0], h0, ZED);                                   \
      s1[qt] = MFMA16(wf[qt][1], h1, ZED);                                   \
      s0[qt] = MFMA16(wf[qt][2], h2, s0[qt]);                                \
      s1[qt] = MFMA16(wf[qt][3], h3, s1[qt]);                                \
    }                                                                        \
    f32x4 pre0 = s0[0] + s1[0];                                              \
    f32x4 pre1 = s0[1] + s1[1];                                              \
    f32x4 pre2 = s0[2] + s1[2];                                              \
    f32x4 pre3 = s0[3] + s1[3];                                              \
    f32x4 pA  = (q & 1) ? pre1 : pre0;                                       \
    f32x4 pB  = (q & 1) ? pre3 : pre2;                                       \
    f32x4 pre = (q & 2) ? pB : pA;                                           \
    float gi = pre[0] + (float)xv[0];                                        \
    float gf = pre[1] + (float)xv[1];                                        \
    float gG = pre[2] + (float)xv[2];                                        \
    float go = pre[3] + (float)xv[3];                                        \
    float is = fast_sig(gi);                                                 \
    float fs = fast_sig(gf);                                                 \
    float gt = fast_tanh(gG);                                                \
    float os = fast_sig(go);                                                 \
    c = fs * c + is * gt;                                                    \
    float hval = os * fast_tanh(c);                                          \
    if (writer) {                                                            \
      hbuf[WB][uu] = (f16)hval;                                              \
      out[(size_t)(b * T_ + (t)) * 256 + dir * 128 + uu] = hval;             \
    }                                                                        \
    BARRIER_LDS();                                                           \
  }

  for (int tt = 0; tt < T_; tt += 2) {
    STEP(tt,     pa, 0, 1)
    STEP(tt + 1, pb, 1, 0)
  }
#undef STEP
}

// ---------------------------------------------------------------------------
extern "C" void kernel_launch(void* const* d_in, const int* in_sizes, int n_in,
                              void* d_out, int out_size, void* d_ws, size_t ws_size,
                              hipStream_t stream) {
  const float* x      = (const float*)d_in[0];
  const int*   lengths= (const int*)  d_in[1];
  const float* Wf_ih  = (const float*)d_in[2];
  const float* Wf_hh  = (const float*)d_in[3];
  const float* bf_ih  = (const float*)d_in[4];
  const float* bf_hh  = (const float*)d_in[5];
  const float* Wb_ih  = (const float*)d_in[6];
  const float* Wb_hh  = (const float*)d_in[7];
  const float* bb_ih  = (const float*)d_in[8];
  const float* bb_hh  = (const float*)d_in[9];
  float* out = (float*)d_out;
  f16*   xg  = (f16*)d_ws;   // needs B*T*1024*2 = 134,217,728 bytes

  (void)in_sizes; (void)n_in; (void)out_size; (void)ws_size;

  xg_gemm<<<dim3(8, 512), 256, 0, stream>>>(x, Wf_ih, Wb_ih,
                                            bf_ih, bf_hh, bb_ih, bb_hh, xg);
  birnn_rec<<<dim3(64), 512, 0, stream>>>(xg, Wf_hh, Wb_hh, lengths, out);
}